// Round 4
// baseline (244.614 us; speedup 1.0000x reference)
//
#include <hip/hip_runtime.h>

#define N_ENT 40000
#define NB 64
#define BODY_LEN 3
#define N_REL 48
#define NUM_POS 24
#define THR 1e-20f

#define NBK 157          // buckets of 256 entities: ceil(40000/256)
#define SPLIT 3          // item-stream slices per bucket in k_bstep
#define PA_BLOCKS 320

// mem layout: entity-major, mem[ent*64 + b]
// item (bucket-grouped, unsorted within bucket): uint2 {
//   meta = nbr | (rEff<<16) | (ownerLow8<<24),  val = bits(v) }
//   owner = bucket*256 + ownerLow8; forward item: owner=h, nbr=t, rEff=r;
//   reverse item: owner=t, nbr=h, rEff=r+NUM_POS. killed edges: v=0.

__global__ void k_zero(int* __restrict__ bktCnt, float* __restrict__ sums) {
    int t = threadIdx.x;
    if (t < NBK) bktCnt[t] = 0;
    if (t < NB) sums[t] = 0.0f;
}

// bucket histogram, LDS-aggregated (replaces k_count's 600k global atomics)
__global__ void k_bhist(const int* __restrict__ eh, const int* __restrict__ et,
                        int* __restrict__ bktCnt, int nE) {
    __shared__ int h[NBK];
    int tid = threadIdx.x;
    for (int i = tid; i < NBK; i += 256) h[i] = 0;
    __syncthreads();
    for (int i = blockIdx.x * 256 + tid; i < nE; i += gridDim.x * 256) {
        atomicAdd(&h[eh[i] >> 8], 1);
        atomicAdd(&h[et[i] >> 8], 1);
    }
    __syncthreads();
    for (int i = tid; i < NBK; i += 256)
        if (h[i]) atomicAdd(&bktCnt[i], h[i]);
}

// exclusive scan over 157 bucket counts -> bktBase[0..NBK], bktCur init
__global__ void k_bscan(const int* __restrict__ bktCnt, int* __restrict__ bktBase,
                        int* __restrict__ bktCur) {
    __shared__ int s[256];
    int t = threadIdx.x;
    int v = (t < NBK) ? bktCnt[t] : 0;
    s[t] = v;
    __syncthreads();
    for (int off = 1; off < 256; off <<= 1) {
        int add = (t >= off) ? s[t - off] : 0;
        __syncthreads();
        s[t] += add;
        __syncthreads();
    }
    if (t < NBK) {
        int ex = s[t] - v;
        bktBase[t] = ex;
        bktCur[t] = ex;
    }
    if (t == NBK - 1) bktBase[NBK] = s[t];   // total = 2*nE
}

// bucket-scatter: per block, LDS histogram of its chunk -> reserve contiguous
// per-bucket regions (1 global atomic per block-bucket) -> write items in runs.
// Kill-check folded in (killed stored with v=0).
__global__ void k_passA(const int* __restrict__ qh, const int* __restrict__ qr,
                        const int* __restrict__ tq, const int* __restrict__ eh,
                        const int* __restrict__ et, const int* __restrict__ er,
                        const float* __restrict__ ev, int* __restrict__ bktCur,
                        uint2* __restrict__ items, int nE) {
    __shared__ long long s_key[NB];
    __shared__ int h[NBK];
    __shared__ int myB[NBK];
    int tid = threadIdx.x;
    if (tid < NB)
        s_key[tid] = ((long long)qh[tid] << 32) | ((long long)tq[tid] << 8) | (long long)qr[tid];
    for (int i = tid; i < NBK; i += 256) h[i] = 0;
    __syncthreads();
    int chunk = (nE + PA_BLOCKS - 1) / PA_BLOCKS;
    int b0 = blockIdx.x * chunk;
    int b1 = min(nE, b0 + chunk);
    for (int i = b0 + tid; i < b1; i += 256) {
        atomicAdd(&h[eh[i] >> 8], 1);
        atomicAdd(&h[et[i] >> 8], 1);
    }
    __syncthreads();
    for (int i = tid; i < NBK; i += 256) {
        int c = h[i];
        myB[i] = c ? atomicAdd(&bktCur[i], c) : 0;
        h[i] = 0;                       // reuse as per-block rank cursor
    }
    __syncthreads();
    for (int i = b0 + tid; i < b1; i += 256) {
        int hh = eh[i], te = et[i], r = er[i];
        long long k = ((long long)hh << 32) | ((long long)te << 8) | (long long)r;
        bool killed = false;
#pragma unroll
        for (int b = 0; b < NB; ++b) killed |= (s_key[b] == k);
        unsigned vb = killed ? 0u : __float_as_uint(ev[i]);
        int bk1 = hh >> 8;
        int rk1 = atomicAdd(&h[bk1], 1);
        items[myB[bk1] + rk1] =
            make_uint2((unsigned)te | ((unsigned)r << 16) | ((unsigned)(hh & 255) << 24), vb);
        int bk2 = te >> 8;
        int rk2 = atomicAdd(&h[bk2], 1);
        items[myB[bk2] + rk2] =
            make_uint2((unsigned)hh | ((unsigned)(r + NUM_POS) << 16) | ((unsigned)(te & 255) << 24), vb);
    }
}

// step 0 fused: nxt = one_hot(qh) * decay0; writes active[] bitmap (= qh set)
__global__ void k_init_decay(const int* __restrict__ qh, const float* __restrict__ attn,
                             float* __restrict__ nxt, unsigned char* __restrict__ active) {
    __shared__ float s_d[NB];
    __shared__ int s_q[NB];
    int tid = threadIdx.x;
    if (tid < NB) {
        s_d[tid] = attn[tid * (BODY_LEN * N_REL) + 0 * N_REL + (N_REL - 1)];
        s_q[tid] = qh[tid];
    }
    __syncthreads();
    int i4 = blockIdx.x * 256 + tid;
    int ent = (i4 * 4) >> 6;
    int b0 = (i4 * 4) & 63;
    float4 w;
    w.x = (s_q[b0 + 0] == ent) ? s_d[b0 + 0] : 0.0f;
    w.y = (s_q[b0 + 1] == ent) ? s_d[b0 + 1] : 0.0f;
    w.z = (s_q[b0 + 2] == ent) ? s_d[b0 + 2] : 0.0f;
    w.w = (s_q[b0 + 3] == ent) ? s_d[b0 + 3] : 0.0f;
    ((float4*)nxt)[i4] = w;
    bool nz = (s_q[b0 + 0] == ent) | (s_q[b0 + 1] == ent) |
              (s_q[b0 + 2] == ent) | (s_q[b0 + 3] == ent);
    unsigned long long m = __ballot(nz);
    int lane = tid & 63;
    if ((lane & 15) == 0) active[i4 >> 4] = ((m >> lane) & 0xFFFFULL) ? 1 : 0;
}

// nxt = old * decay; active[] = per-entity any-nonzero of OLD row
__global__ void k_decay(const float* __restrict__ oldm, float* __restrict__ nxt,
                        const float* __restrict__ attn, int step,
                        unsigned char* __restrict__ active) {
    __shared__ float s_d[NB];
    int tid = threadIdx.x;
    if (tid < NB)
        s_d[tid] = attn[tid * (BODY_LEN * N_REL) + step * N_REL + (N_REL - 1)];
    __syncthreads();
    int i4 = blockIdx.x * 256 + tid;
    float4 v = ((const float4*)oldm)[i4];
    int b0 = (tid * 4) & 63;
    float4 w;
    w.x = v.x * s_d[b0 + 0];
    w.y = v.y * s_d[b0 + 1];
    w.z = v.z * s_d[b0 + 2];
    w.w = v.w * s_d[b0 + 3];
    ((float4*)nxt)[i4] = w;
    bool nz = (v.x != 0.0f) | (v.y != 0.0f) | (v.z != 0.0f) | (v.w != 0.0f);
    unsigned long long m = __ballot(nz);
    int lane = tid & 63;
    if ((lane & 15) == 0) active[i4 >> 4] = ((m >> lane) & 0xFFFFULL) ? 1 : 0;
}

// bucket-staged message pass: block = (bucket, slice). Stages the bucket's 256
// source rows in LDS once; streams bucket items coalesced; ballot-skips
// inactive owners; per-lane predicated atomics into nxt.
template <bool STEP0>
__global__ __launch_bounds__(256) void k_bstep(
    const uint2* __restrict__ items, const int* __restrict__ bktBase,
    const unsigned char* __restrict__ active, const float* __restrict__ attn,
    int step, const float* __restrict__ oldm, const int* __restrict__ qh,
    float* __restrict__ nxt) {
    __shared__ float s_attn[NB][N_REL + 1];          // 12.5 KB, stride-49 conflict-free
    __shared__ float s_stage[STEP0 ? 64 : 256 * 64]; // 64 KB when staging
    __shared__ unsigned char s_act[256];
    __shared__ int s_any;
    int tid = threadIdx.x;
    int lane = tid & 63;
    int b = blockIdx.x % NBK;
    int part = blockIdx.x / NBK;
    int e0 = b << 8;
    int eCnt = min(256, N_ENT - e0);
    if (tid == 0) s_any = 0;
    __syncthreads();
    for (int k = tid; k < eCnt; k += 256) {
        unsigned char a = active[e0 + k];
        s_act[k] = a;
        if (a) s_any = 1;                // benign race, all write 1
    }
    __syncthreads();
    if (!s_any) return;                  // whole bucket inactive
    for (int idx = tid; idx < NB * N_REL; idx += 256) {
        int bb = idx / N_REL, r = idx % N_REL;
        s_attn[bb][r] = attn[bb * (BODY_LEN * N_REL) + step * N_REL + r];
    }
    if (!STEP0) {
        const float4* src4 = (const float4*)(oldm + (size_t)e0 * 64);
        for (int i = tid; i < eCnt * 16; i += 256) ((float4*)s_stage)[i] = src4[i];
    }
    int myqh = STEP0 ? qh[lane] : 0;
    __syncthreads();
    int ib = bktBase[b];
    int n = bktBase[b + 1] - ib;
    int per = (n + SPLIT - 1) / SPLIT;
    int s0 = part * per;
    int s1 = min(n, s0 + per);
    int wave = tid >> 6;
    for (int base = s0 + wave * 64; base < s1; base += 4 * 64) {
        int i = base + lane;
        uint2 it = (i < s1) ? items[ib + i] : make_uint2(0u, 0u);
        int eL = (int)(it.x >> 24);
        bool act = (i < s1) && s_act[eL] && (it.y != 0u);
        unsigned long long m = __ballot(act);
        while (m) {
            int j = __ffsll((long long)m) - 1;
            m &= m - 1;
            unsigned meta = (unsigned)__shfl((int)it.x, j);
            float v = __uint_as_float((unsigned)__shfl((int)it.y, j));
            int eLj = (int)(meta >> 24);
            float src = STEP0 ? ((e0 + eLj == myqh) ? 1.0f : 0.0f)
                              : s_stage[(eLj << 6) + lane];
            float val = src * v * s_attn[lane][(meta >> 16) & 63];
            if (val != 0.0f)
                atomicAdd(&nxt[(size_t)(meta & 0xFFFFu) * 64 + lane], val);
        }
    }
}

__global__ void k_sums(const float* __restrict__ mem, float* __restrict__ sums) {
    __shared__ float s_s[NB];
    if (threadIdx.x < NB) s_s[threadIdx.x] = 0.0f;
    __syncthreads();
    const float4* m4 = (const float4*)mem;
    const int total4 = NB * N_ENT / 4;
    float4 acc = {0.0f, 0.0f, 0.0f, 0.0f};
    for (int i = blockIdx.x * 256 + threadIdx.x; i < total4; i += gridDim.x * 256) {
        float4 v = m4[i];
        acc.x += v.x; acc.y += v.y; acc.z += v.z; acc.w += v.w;
    }
    int b0 = (threadIdx.x * 4) & 63;
    atomicAdd(&s_s[b0 + 0], acc.x);
    atomicAdd(&s_s[b0 + 1], acc.y);
    atomicAdd(&s_s[b0 + 2], acc.z);
    atomicAdd(&s_s[b0 + 3], acc.w);
    __syncthreads();
    if (threadIdx.x < NB) atomicAdd(&sums[threadIdx.x], s_s[threadIdx.x]);
}

// transpose (ent-major -> batch-major) + normalize; block N_ENT/64 computes the loss
__global__ void k_norm_tr(const float* __restrict__ mem, const float* __restrict__ sums,
                          const int* __restrict__ tt, float* __restrict__ out) {
    if (blockIdx.x == N_ENT / 64) {  // loss block
        int b = threadIdx.x;
        if (b < 64) {
            float p = mem[(size_t)tt[b] * 64 + b] / fmaxf(THR, sums[b]);
            float l = -logf(fmaxf(THR, p));
#pragma unroll
            for (int off = 32; off > 0; off >>= 1) l += __shfl_down(l, off);
            if (b == 0) out[0] = l * (1.0f / 64.0f);
        }
        return;
    }
    __shared__ float tile[64][65];
    __shared__ float s_inv[64];
    int tid = threadIdx.x;
    int e0 = blockIdx.x * 64;
    if (tid < 64) s_inv[tid] = 1.0f / fmaxf(THR, sums[tid]);
    const float4* m4 = (const float4*)(mem + (size_t)e0 * 64);
#pragma unroll
    for (int k = 0; k < 4; ++k) {
        int i4 = k * 256 + tid;
        float4 v = m4[i4];
        int el = i4 >> 4, b0 = (i4 * 4) & 63;
        tile[el][b0 + 0] = v.x; tile[el][b0 + 1] = v.y;
        tile[el][b0 + 2] = v.z; tile[el][b0 + 3] = v.w;
    }
    __syncthreads();
#pragma unroll
    for (int k = 0; k < 16; ++k) {
        int idx = k * 256 + tid;
        int el = idx & 63, b = idx >> 6;
        out[1 + (size_t)b * N_ENT + e0 + el] = tile[el][b] * s_inv[b];
    }
}

extern "C" void kernel_launch(void* const* d_in, const int* in_sizes, int n_in,
                              void* d_out, int out_size, void* d_ws, size_t ws_size,
                              hipStream_t stream) {
    const int*   qh   = (const int*)d_in[0];
    const int*   qr   = (const int*)d_in[1];
    const int*   tt   = (const int*)d_in[2];
    const float* attn = (const float*)d_in[3];
    const int*   eh   = (const int*)d_in[4];
    const int*   et   = (const int*)d_in[5];
    const int*   er   = (const int*)d_in[6];
    const float* ev   = (const float*)d_in[7];
    float* out = (float*)d_out;
    int nE = in_sizes[4];

    const size_t MEM_BYTES = (size_t)NB * N_ENT * sizeof(float);  // 10,240,000
    char* ws = (char*)d_ws;
    int*   bktCnt  = (int*)ws;                            // 157*4
    int*   bktBase = (int*)(ws + 1024);                   // 158*4
    int*   bktCur  = (int*)(ws + 2048);                   // 157*4
    float* sums    = (float*)(ws + 4096);                 // 256 B
    unsigned char* active = (unsigned char*)(ws + 8192);  // 40 KB
    uint2* items   = (uint2*)(ws + (1u << 20));           // 2*nE*8 = 4.8 MB
    float* memA    = (float*)(ws + (8u << 20));           // 10.24 MB
    float* memB;
    size_t needBoth = (size_t)(8u << 20) + 2 * MEM_BYTES;
    if (ws_size >= needBoth)
        memB = (float*)(ws + (8u << 20) + MEM_BYTES);
    else
        memB = out + 1;  // fallback scratch; k_norm_tr overwrites it at the end

    const int NE_F4 = NB * N_ENT / 4 / 256;  // 2500 blocks

    // ---- bucket-grouped edge build ----
    k_zero<<<1, 256, 0, stream>>>(bktCnt, sums);
    k_bhist<<<PA_BLOCKS, 256, 0, stream>>>(eh, et, bktCnt, nE);
    k_bscan<<<1, 256, 0, stream>>>(bktCnt, bktBase, bktCur);
    k_passA<<<PA_BLOCKS, 256, 0, stream>>>(qh, qr, tt, eh, et, er, ev, bktCur, items, nE);

    // ---- step 0: virtual one-hot source; nxt = memA ----
    k_init_decay<<<NE_F4, 256, 0, stream>>>(qh, attn, memA, active);
    k_bstep<true><<<NBK * SPLIT, 256, 0, stream>>>(items, bktBase, active, attn, 0,
                                                   nullptr, qh, memA);
    // ---- steps 1,2: ping-pong memA <-> memB; final lands in memA ----
    float* curm = memA;
    float* nxtm = memB;
    for (int s = 1; s < BODY_LEN; ++s) {
        k_decay<<<NE_F4, 256, 0, stream>>>(curm, nxtm, attn, s, active);
        k_bstep<false><<<NBK * SPLIT, 256, 0, stream>>>(items, bktBase, active, attn, s,
                                                        curm, nullptr, nxtm);
        float* tmp = curm; curm = nxtm; nxtm = tmp;
    }
    // curm == memA (final, ent-major, unnormalized)

    k_sums<<<128, 256, 0, stream>>>(curm, sums);
    k_norm_tr<<<N_ENT / 64 + 1, 256, 0, stream>>>(curm, sums, tt, out);
}

// Round 5
// 200.134 us; speedup vs baseline: 1.2222x; 1.2222x over previous
//
#include <hip/hip_runtime.h>

#define N_ENT 40000
#define NB 64
#define BODY_LEN 3
#define N_REL 48
#define NUM_POS 24
#define THR 1e-20f

#define NBK 157          // buckets of 256 entities: ceil(40000/256)
#define PA_BLOCKS 320
#define DEC_BLOCKS 320
#define FLIST_LDS 192    // per-block flagged-entity bound: 8 iters * 16 = 128

// mem layout: entity-major, mem[ent*64 + b]
// item/CSR slot: uint2 { meta = nbr | (rEff<<16) | (ownerLow8<<24), val = bits(v) }
//   owner = bucket*256 + ownerLow8; forward: owner=h, nbr=t, rEff=r;
//   reverse: owner=t, nbr=h, rEff=r+NUM_POS. killed edges: v=0.

__global__ void k_zero(int* __restrict__ bktCnt, int* __restrict__ fcnt,
                       float* __restrict__ sums) {
    int t = threadIdx.x;
    if (t < NBK) bktCnt[t] = 0;
    if (t < 3) fcnt[t] = 0;
    if (t < NB) sums[t] = 0.0f;
}

// bucket histogram, LDS-aggregated (no 600k global atomic storm)
__global__ void k_bhist(const int* __restrict__ eh, const int* __restrict__ et,
                        int* __restrict__ bktCnt, int nE) {
    __shared__ int h[NBK];
    int tid = threadIdx.x;
    for (int i = tid; i < NBK; i += 256) h[i] = 0;
    __syncthreads();
    for (int i = blockIdx.x * 256 + tid; i < nE; i += gridDim.x * 256) {
        atomicAdd(&h[eh[i] >> 8], 1);
        atomicAdd(&h[et[i] >> 8], 1);
    }
    __syncthreads();
    for (int i = tid; i < NBK; i += 256)
        if (h[i]) atomicAdd(&bktCnt[i], h[i]);
}

// exclusive scan over 157 bucket counts -> bktBase[0..NBK], bktCur init; offs[N_ENT]
__global__ void k_bscan(const int* __restrict__ bktCnt, int* __restrict__ bktBase,
                        int* __restrict__ bktCur, int* __restrict__ offs) {
    __shared__ int s[256];
    int t = threadIdx.x;
    int v = (t < NBK) ? bktCnt[t] : 0;
    s[t] = v;
    __syncthreads();
    for (int off = 1; off < 256; off <<= 1) {
        int add = (t >= off) ? s[t - off] : 0;
        __syncthreads();
        s[t] += add;
        __syncthreads();
    }
    if (t < NBK) {
        int ex = s[t] - v;
        bktBase[t] = ex;
        bktCur[t] = ex;
    }
    if (t == NBK - 1) {
        bktBase[NBK] = s[t];
        offs[N_ENT] = s[t];            // total = 2*nE
    }
}

// pass A: bucket-grouped scatter. Per block: LDS histogram of its chunk ->
// reserve contiguous per-bucket regions (1 global atomic per block-bucket) ->
// write items in ~96B runs. Kill-check folded in (killed stored with v=0).
__global__ void k_passA(const int* __restrict__ qh, const int* __restrict__ qr,
                        const int* __restrict__ tq, const int* __restrict__ eh,
                        const int* __restrict__ et, const int* __restrict__ er,
                        const float* __restrict__ ev, int* __restrict__ bktCur,
                        uint2* __restrict__ items, int nE) {
    __shared__ long long s_key[NB];
    __shared__ int h[NBK];
    __shared__ int myB[NBK];
    int tid = threadIdx.x;
    if (tid < NB)
        s_key[tid] = ((long long)qh[tid] << 32) | ((long long)tq[tid] << 8) | (long long)qr[tid];
    for (int i = tid; i < NBK; i += 256) h[i] = 0;
    __syncthreads();
    int chunk = (nE + PA_BLOCKS - 1) / PA_BLOCKS;
    int b0 = blockIdx.x * chunk;
    int b1 = min(nE, b0 + chunk);
    for (int i = b0 + tid; i < b1; i += 256) {
        atomicAdd(&h[eh[i] >> 8], 1);
        atomicAdd(&h[et[i] >> 8], 1);
    }
    __syncthreads();
    for (int i = tid; i < NBK; i += 256) {
        int c = h[i];
        myB[i] = c ? atomicAdd(&bktCur[i], c) : 0;
        h[i] = 0;                       // reuse as per-block rank cursor
    }
    __syncthreads();
    for (int i = b0 + tid; i < b1; i += 256) {
        int hh = eh[i], te = et[i], r = er[i];
        long long k = ((long long)hh << 32) | ((long long)te << 8) | (long long)r;
        bool killed = false;
#pragma unroll
        for (int b = 0; b < NB; ++b) killed |= (s_key[b] == k);
        unsigned vb = killed ? 0u : __float_as_uint(ev[i]);
        int bk1 = hh >> 8;
        int rk1 = atomicAdd(&h[bk1], 1);
        items[myB[bk1] + rk1] =
            make_uint2((unsigned)te | ((unsigned)r << 16) | ((unsigned)(hh & 255) << 24), vb);
        int bk2 = te >> 8;
        int rk2 = atomicAdd(&h[bk2], 1);
        items[myB[bk2] + rk2] =
            make_uint2((unsigned)hh | ((unsigned)(r + NUM_POS) << 16) | ((unsigned)(te & 255) << 24), vb);
    }
}

// pass B: one block per bucket. LDS histogram of 256 owners -> scan ->
// per-entity offs[] -> scatter items into final CSR slots (block-private
// contiguous span => full-line writes).
__global__ void k_passB(const uint2* __restrict__ itemsA, const int* __restrict__ bktBase,
                        int* __restrict__ offs, uint2* __restrict__ csr) {
    __shared__ int cnt[256];
    __shared__ int sc[256];
    int tid = threadIdx.x;
    int b = blockIdx.x;
    int e0 = b << 8;
    int eCnt = min(256, N_ENT - e0);
    cnt[tid] = 0;
    __syncthreads();
    int ib = bktBase[b];
    int n = bktBase[b + 1] - ib;
    for (int i = tid; i < n; i += 256)
        atomicAdd(&cnt[itemsA[ib + i].x >> 24], 1);
    __syncthreads();
    int v = cnt[tid];
    sc[tid] = v;
    __syncthreads();
    for (int off = 1; off < 256; off <<= 1) {
        int add = (tid >= off) ? sc[tid - off] : 0;
        __syncthreads();
        sc[tid] += add;
        __syncthreads();
    }
    int ex = sc[tid] - v;               // intra-bucket exclusive offset
    if (tid < eCnt) offs[e0 + tid] = ib + ex;
    cnt[tid] = ex;                      // reuse as scatter cursor
    __syncthreads();
    for (int i = tid; i < n; i += 256) {
        uint2 it = itemsA[ib + i];
        int k = (int)(it.x >> 24);
        int p = atomicAdd(&cnt[k], 1);
        csr[ib + p] = it;
    }
}

// ---- frontier aggregation (block-local; ONE global atomic per block) ----
__device__ __forceinline__ void flag_entities(unsigned long long m, int lane,
                                              int ent, int* s_cnt, int* s_list) {
    bool flag = ((lane & 15) == 0) && ((m >> lane) & 0xFFFFULL);
    unsigned long long am = __ballot(flag);
    if (am) {
        int leader = __ffsll((long long)am) - 1;
        int lb = 0;
        if (lane == leader) lb = atomicAdd(s_cnt, __popcll(am));
        lb = __shfl(lb, leader);
        if (flag) {
            int rank = __popcll(am & ((1ULL << lane) - 1ULL));
            s_list[lb + rank] = ent;
        }
    }
}

// step 0 fused: nxt = one_hot(qh) * decay0; appends step-0 frontier (= qh set)
__global__ void k_init_decay(const int* __restrict__ qh, const float* __restrict__ attn,
                             float* __restrict__ nxt, int* __restrict__ fcnt,
                             int* __restrict__ flist) {
    __shared__ float s_d[NB];
    __shared__ int s_q[NB];
    __shared__ int s_list[FLIST_LDS];
    __shared__ int s_cnt, s_gbase;
    int tid = threadIdx.x;
    if (tid < NB) {
        s_d[tid] = attn[tid * (BODY_LEN * N_REL) + 0 * N_REL + (N_REL - 1)];
        s_q[tid] = qh[tid];
    }
    if (tid == 0) s_cnt = 0;
    __syncthreads();
    int lane = tid & 63;
    const int total4 = NB * N_ENT / 4;       // 640000, divisible by 256
    for (int i4 = blockIdx.x * 256 + tid; i4 < total4; i4 += gridDim.x * 256) {
        int ent = (i4 * 4) >> 6;
        int b0 = (i4 * 4) & 63;
        float4 w;
        w.x = (s_q[b0 + 0] == ent) ? s_d[b0 + 0] : 0.0f;
        w.y = (s_q[b0 + 1] == ent) ? s_d[b0 + 1] : 0.0f;
        w.z = (s_q[b0 + 2] == ent) ? s_d[b0 + 2] : 0.0f;
        w.w = (s_q[b0 + 3] == ent) ? s_d[b0 + 3] : 0.0f;
        ((float4*)nxt)[i4] = w;
        bool nz = (s_q[b0 + 0] == ent) | (s_q[b0 + 1] == ent) |
                  (s_q[b0 + 2] == ent) | (s_q[b0 + 3] == ent);
        unsigned long long m = __ballot(nz);
        flag_entities(m, lane, ent, &s_cnt, s_list);
    }
    __syncthreads();
    if (tid == 0 && s_cnt) s_gbase = atomicAdd(fcnt, s_cnt);
    __syncthreads();
    for (int i = tid; i < s_cnt; i += 256) flist[s_gbase + i] = s_list[i];
}

// nxt = old * decay; appends frontier of entities with any nonzero lane in old
__global__ void k_decay(const float* __restrict__ oldm, float* __restrict__ nxt,
                        const float* __restrict__ attn, int step,
                        int* __restrict__ fcnt, int* __restrict__ flist) {
    __shared__ float s_d[NB];
    __shared__ int s_list[FLIST_LDS];
    __shared__ int s_cnt, s_gbase;
    int tid = threadIdx.x;
    if (tid < NB)
        s_d[tid] = attn[tid * (BODY_LEN * N_REL) + step * N_REL + (N_REL - 1)];
    if (tid == 0) s_cnt = 0;
    __syncthreads();
    int lane = tid & 63;
    const int total4 = NB * N_ENT / 4;       // 640000, divisible by 256
    for (int i4 = blockIdx.x * 256 + tid; i4 < total4; i4 += gridDim.x * 256) {
        float4 v = ((const float4*)oldm)[i4];
        int b0 = (tid * 4) & 63;
        float4 w;
        w.x = v.x * s_d[b0 + 0];
        w.y = v.y * s_d[b0 + 1];
        w.z = v.z * s_d[b0 + 2];
        w.w = v.w * s_d[b0 + 3];
        ((float4*)nxt)[i4] = w;
        bool nz = (v.x != 0.0f) | (v.y != 0.0f) | (v.z != 0.0f) | (v.w != 0.0f);
        unsigned long long m = __ballot(nz);
        flag_entities(m, lane, (i4 * 4) >> 6, &s_cnt, s_list);
    }
    __syncthreads();
    if (tid == 0 && s_cnt) s_gbase = atomicAdd(fcnt, s_cnt);
    __syncthreads();
    for (int i = tid; i < s_cnt; i += 256) flist[s_gbase + i] = s_list[i];
}

// frontier-centric message pass: one wave per active entity (grid-strided).
template <bool STEP0>
__global__ __launch_bounds__(256) void k_fstep(
    const uint2* __restrict__ csr, const int* __restrict__ offs,
    const int* __restrict__ flist, const int* __restrict__ fcnt,
    const float* __restrict__ attn, int step,
    const float* __restrict__ oldm, const int* __restrict__ qh,
    float* __restrict__ nxt) {
    __shared__ float s_attn[NB][N_REL + 1];  // stride 49: conflict-free
    int tid = threadIdx.x;
    for (int idx = tid; idx < NB * N_REL; idx += 256) {
        int b = idx / N_REL, r = idx % N_REL;
        s_attn[b][r] = attn[b * (BODY_LEN * N_REL) + step * N_REL + r];
    }
    __syncthreads();
    int lane = tid & 63;
    int myqh = STEP0 ? qh[lane] : 0;
    int n = *fcnt;
    int w = (blockIdx.x * 256 + tid) >> 6;
    int nW = (gridDim.x * 256) >> 6;
    for (int f = w; f < n; f += nW) {
        int e = flist[f];
        float src = STEP0 ? ((myqh == e) ? 1.0f : 0.0f)
                          : oldm[(size_t)e * 64 + lane];
        int base = offs[e];
        int cnt = offs[e + 1] - base;
        for (int k0 = 0; k0 < cnt; k0 += 64) {
            uint2 slot = make_uint2(0u, 0u);
            if (k0 + lane < cnt) slot = csr[base + k0 + lane];
            int lim = min(64, cnt - k0);
            for (int j = 0; j < lim; ++j) {
                unsigned meta = (unsigned)__shfl((int)slot.x, j);
                float v = __uint_as_float((unsigned)__shfl((int)slot.y, j));
                if (v == 0.0f) continue;  // killed edge (wave-uniform)
                float val = src * v * s_attn[lane][(meta >> 16) & 63];
                if (val != 0.0f)
                    atomicAdd(&nxt[(size_t)(meta & 0xFFFFu) * 64 + lane], val);
            }
        }
    }
}

__global__ void k_sums(const float* __restrict__ mem, float* __restrict__ sums) {
    __shared__ float s_s[NB];
    if (threadIdx.x < NB) s_s[threadIdx.x] = 0.0f;
    __syncthreads();
    const float4* m4 = (const float4*)mem;
    const int total4 = NB * N_ENT / 4;
    float4 acc = {0.0f, 0.0f, 0.0f, 0.0f};
    for (int i = blockIdx.x * 256 + threadIdx.x; i < total4; i += gridDim.x * 256) {
        float4 v = m4[i];
        acc.x += v.x; acc.y += v.y; acc.z += v.z; acc.w += v.w;
    }
    int b0 = (threadIdx.x * 4) & 63;   // stride is multiple of 16 float4s -> b fixed
    atomicAdd(&s_s[b0 + 0], acc.x);
    atomicAdd(&s_s[b0 + 1], acc.y);
    atomicAdd(&s_s[b0 + 2], acc.z);
    atomicAdd(&s_s[b0 + 3], acc.w);
    __syncthreads();
    if (threadIdx.x < NB) atomicAdd(&sums[threadIdx.x], s_s[threadIdx.x]);
}

// transpose (ent-major -> batch-major) + normalize; block N_ENT/64 computes the loss
__global__ void k_norm_tr(const float* __restrict__ mem, const float* __restrict__ sums,
                          const int* __restrict__ tt, float* __restrict__ out) {
    if (blockIdx.x == N_ENT / 64) {  // loss block
        int b = threadIdx.x;
        if (b < 64) {
            float p = mem[(size_t)tt[b] * 64 + b] / fmaxf(THR, sums[b]);
            float l = -logf(fmaxf(THR, p));
#pragma unroll
            for (int off = 32; off > 0; off >>= 1) l += __shfl_down(l, off);
            if (b == 0) out[0] = l * (1.0f / 64.0f);
        }
        return;
    }
    __shared__ float tile[64][65];
    __shared__ float s_inv[64];
    int tid = threadIdx.x;
    int e0 = blockIdx.x * 64;
    if (tid < 64) s_inv[tid] = 1.0f / fmaxf(THR, sums[tid]);
    const float4* m4 = (const float4*)(mem + (size_t)e0 * 64);
#pragma unroll
    for (int k = 0; k < 4; ++k) {
        int i4 = k * 256 + tid;
        float4 v = m4[i4];
        int el = i4 >> 4, b0 = (i4 * 4) & 63;
        tile[el][b0 + 0] = v.x; tile[el][b0 + 1] = v.y;
        tile[el][b0 + 2] = v.z; tile[el][b0 + 3] = v.w;
    }
    __syncthreads();
#pragma unroll
    for (int k = 0; k < 16; ++k) {
        int idx = k * 256 + tid;
        int el = idx & 63, b = idx >> 6;
        out[1 + (size_t)b * N_ENT + e0 + el] = tile[el][b] * s_inv[b];
    }
}

extern "C" void kernel_launch(void* const* d_in, const int* in_sizes, int n_in,
                              void* d_out, int out_size, void* d_ws, size_t ws_size,
                              hipStream_t stream) {
    const int*   qh   = (const int*)d_in[0];
    const int*   qr   = (const int*)d_in[1];
    const int*   tt   = (const int*)d_in[2];
    const float* attn = (const float*)d_in[3];
    const int*   eh   = (const int*)d_in[4];
    const int*   et   = (const int*)d_in[5];
    const int*   er   = (const int*)d_in[6];
    const float* ev   = (const float*)d_in[7];
    float* out = (float*)d_out;
    int nE = in_sizes[4];

    const size_t MEM_BYTES = (size_t)NB * N_ENT * sizeof(float);  // 10,240,000
    char* ws = (char*)d_ws;
    int*   offs    = (int*)ws;                        // (N_ENT+1)*4 = 160 KB
    int*   flist   = (int*)(ws + (192u << 10));       // 160 KB
    int*   bktCnt  = (int*)(ws + (384u << 10));       // 157*4
    int*   bktBase = (int*)(ws + (388u << 10));       // 158*4
    int*   bktCur  = (int*)(ws + (392u << 10));       // 157*4
    int*   fcnt    = (int*)(ws + (396u << 10));       // 12 B
    float* sums    = (float*)(ws + (400u << 10));     // 256 B
    uint2* csr     = (uint2*)(ws + (1u << 20));       // 2*nE*8 = 4.8 MB (< 5 MB slot)
    float* memA    = (float*)(ws + (6u << 20));       // 10.24 MB
    float* memB;
    uint2* itemsA;
    size_t itemsBytes = (size_t)2 * nE * sizeof(uint2);
    size_t needBoth = (size_t)(6u << 20) + 2 * MEM_BYTES + itemsBytes;
    if (ws_size >= needBoth) {
        memB   = (float*)(ws + (6u << 20) + MEM_BYTES);
        itemsA = (uint2*)(ws + (6u << 20) + 2 * MEM_BYTES);
    } else {
        // out+1 region (10.24 MB) is used twice with disjoint lifetimes:
        // itemsA dies after k_passB (dispatch 5); memB first written at
        // k_decay step 1 (dispatch 8). k_norm_tr overwrites out at the end.
        memB   = out + 1;
        itemsA = (uint2*)(out + 1);
    }

    // ---- CSR build via two-pass bucket sort ----
    k_zero<<<1, 256, 0, stream>>>(bktCnt, fcnt, sums);
    k_bhist<<<PA_BLOCKS, 256, 0, stream>>>(eh, et, bktCnt, nE);
    k_bscan<<<1, 256, 0, stream>>>(bktCnt, bktBase, bktCur, offs);
    k_passA<<<PA_BLOCKS, 256, 0, stream>>>(qh, qr, tt, eh, et, er, ev, bktCur, itemsA, nE);
    k_passB<<<NBK, 256, 0, stream>>>(itemsA, bktBase, offs, csr);

    // ---- step 0: virtual one-hot source; nxt = memA ----
    k_init_decay<<<DEC_BLOCKS, 256, 0, stream>>>(qh, attn, memA, fcnt + 0, flist);
    k_fstep<true><<<16, 256, 0, stream>>>(csr, offs, flist, fcnt + 0, attn, 0,
                                          nullptr, qh, memA);
    // ---- steps 1,2: ping-pong memA <-> memB; final lands in memA ----
    float* curm = memA;
    float* nxtm = memB;
    for (int s = 1; s < BODY_LEN; ++s) {
        k_decay<<<DEC_BLOCKS, 256, 0, stream>>>(curm, nxtm, attn, s, fcnt + s, flist);
        k_fstep<false><<<1024, 256, 0, stream>>>(csr, offs, flist, fcnt + s, attn, s,
                                                 curm, nullptr, nxtm);
        float* tmp = curm; curm = nxtm; nxtm = tmp;
    }
    // curm == memA (final, ent-major, unnormalized)

    k_sums<<<128, 256, 0, stream>>>(curm, sums);
    k_norm_tr<<<N_ENT / 64 + 1, 256, 0, stream>>>(curm, sums, tt, out);
}